// Round 8
// baseline (88.528 us; speedup 1.0000x reference)
//
#include <hip/hip_runtime.h>
#include <stdint.h>

#define BATCH     10000
#define NUM_TREES 1000
#define NUM_NODES 511
#define NFEAT     256
#define DEPTH     8
#define FLAT_NODES (NUM_TREES * NUM_NODES)

// ---------------- 2-level fused record layout in d_ws ----------------
// Implicit depth-8 tree. Records exist at even depths {0,2,4,6}:
//   rec = {f32 thr_p, f32 thr_l, f32 thr_r, u32 f_p|f_l<<8|f_r<<16}
// rec index = EBASE[d/2] + local, EBASE = {0,1,5,21}; 85 recs = 1360 B/tree.
// One b128 read + 2 compares descends 2 levels: local' = 4*local + 2c0 + c1.
// Leaf (depth 8): vleaf[local] per tree (256 f32 = 1024 B).
#define TREE_BYTES 1360
#define VLEAF_OFF  ((size_t)NUM_TREES * TREE_BYTES)          // 1,360,000
#define WS_NEEDED  (VLEAF_OFF + (size_t)NUM_TREES * 256 * 4) // 2,384,000

// ---------------- traverse geometry ----------------
#define BT 64            // batch rows per tile
#define TT 64            // trees per block
#define YT 2             // batch tiles per block (node staging amortized)
#define NTHREADS 1024    // 16 waves
#define XS_BYTES  (NFEAT * 64 * 4)               // 65536, [feat][64] CLEAN
#define NS_BYTES  (TT * TREE_BYTES)              // 87040
#define SH_BYTES  (XS_BYTES + NS_BYTES)          // 152576 <= 160 KiB
#define NCHUNK    (NS_BYTES / 16)                // 5440 16B chunks

// async global->LDS copy, 16B per lane (dest = uniform base + lane*16)
__device__ __forceinline__ void glds16(const void* g, void* l) {
  __builtin_amdgcn_global_load_lds(
      (const __attribute__((address_space(1))) unsigned int*)g,
      (__attribute__((address_space(3))) unsigned int*)l, 16, 0, 0);
}

// ================= prepack: BFS-unroll into 2-level records =================
__global__ __launch_bounds__(256)
void unroll_kernel(const float* __restrict__ thr,
                   const int* __restrict__ feats,
                   const int* __restrict__ lefts,
                   const int* __restrict__ rights,
                   const float* __restrict__ values,
                   unsigned char* __restrict__ ws) {
  __shared__ uint16_t n_s[4][512];
  const int wv = threadIdx.x >> 6, lane = threadIdx.x & 63;
  const int tree = blockIdx.x * 4 + wv;          // grid=250 -> always < 1000
  const int base = tree * NUM_NODES;
  uint16_t* n = n_s[wv];
  uint4* rec   = (uint4*)(ws + (size_t)tree * TREE_BYTES);
  float* vleaf = (float*)(ws + VLEAF_OFF + (size_t)tree * 1024);

  if (lane == 0) n[0] = 0;
  __syncthreads();
  const int EBASE[4] = {0, 1, 5, 21};
  #pragma unroll
  for (int d = 0; d < 8; ++d) {
    const int lvl = (1 << d) - 1, cnt = 1 << d;
    for (int i = lane; i < cnt; i += 64) {
      int p  = lvl + i;
      int np = n[p];
      int nl = lefts[base + np], nr = rights[base + np];
      n[2 * p + 1] = (uint16_t)nl;
      n[2 * p + 2] = (uint16_t)nr;
      if ((d & 1) == 0) {
        uint32_t f3 = (uint32_t)feats[base + np] |
                      ((uint32_t)feats[base + nl] << 8) |
                      ((uint32_t)feats[base + nr] << 16);
        rec[EBASE[d >> 1] + i] =
            make_uint4(__float_as_uint(thr[base + np]),
                       __float_as_uint(thr[base + nl]),
                       __float_as_uint(thr[base + nr]), f3);
      }
    }
    __syncthreads();
  }
  #pragma unroll
  for (int i = lane; i < 256; i += 64)
    vleaf[i] = values[base + n[255 + i]];
}

// ================= main traversal =================
__global__ __launch_bounds__(NTHREADS, 1)
void traverse64(const float* __restrict__ x,
                const unsigned char* __restrict__ ws,
                float* __restrict__ out) {
  extern __shared__ unsigned char smem[];
  float* x_s = (float*)smem;                     // [256][64] feat-major, clean
  unsigned char* nodes = smem + XS_BYTES;        // 64 trees * 1360 B

  const int tid  = threadIdx.x;
  const int wid  = tid >> 6;
  const int lane = tid & 63;
  const int t0   = blockIdx.x * TT;

  // ---- node staging: async global->LDS b128, linear (once per block) ----
  {
    const unsigned char* src = ws + (size_t)t0 * TREE_BYTES;
    #pragma unroll
    for (int k = 0; k < 6; ++k) {
      int fi = tid + k * NTHREADS;
      if (fi < NCHUNK) glds16(src + (size_t)fi * 16, nodes + (size_t)fi * 16);
    }
  }

  // ---- x staging mapping: conflict-free [feat][64] writes ----
  // row = 32*(wid&1) + (lane>>1): 32 distinct rows/wave, 2 lanes each ->
  // ds_write bank = row%32, 2-way = free. Global: 32x32B segments/instr.
  const int srow  = 32 * (wid & 1) + (lane >> 1);
  const int scol0 = (lane & 1) + 2 * (wid >> 1);   // f4 col, +16p
  const float4* xg = (const float4*)x;
  float4 xv[4];

  auto xload = [&](int b0) {
    #pragma unroll
    for (int p = 0; p < 4; ++p) {
      int gb = b0 + srow;
      int c  = scol0 + 16 * p;
      xv[p] = (gb < BATCH) ? xg[(size_t)gb * 64 + c]
                           : make_float4(0.f, 0.f, 0.f, 0.f);
    }
  };
  auto xwrite = [&]() {
    #pragma unroll
    for (int p = 0; p < 4; ++p) {
      int c = scol0 + 16 * p;
      int o = (4 * c) * 64 + srow;       // feat=4c+k at o + 64k
      x_s[o]       = xv[p].x;
      x_s[o + 64]  = xv[p].y;
      x_s[o + 128] = xv[p].z;
      x_s[o + 192] = xv[p].w;
    }
  };

  const int bbase = blockIdx.y * (YT * BT);
  xload(bbase);
  xwrite();
  __syncthreads();           // nodes (vmcnt-drained) + x_s ready

  const unsigned char* nb = nodes + (size_t)(4 * wid) * TREE_BYTES;
  const float* vl = (const float*)(ws + VLEAF_OFF);
  const int gt0 = t0 + 4 * wid;

  for (int yt = 0; yt < YT; ++yt) {
    const int b0 = bbase + yt * BT;
    if (yt + 1 < YT) xload(b0 + BT);   // issue-early; hides under traversal

    // ---- traverse 4 chains (ILP=4); lane = batch row ----
    int loc[4] = {0, 0, 0, 0};
    #pragma unroll
    for (int it = 0; it < 4; ++it) {
      const int eoff = (it == 0) ? 0 : (it == 1) ? 16 : (it == 2) ? 80 : 336;
      uint4 r[4];
      #pragma unroll
      for (int c = 0; c < 4; ++c)
        r[c] = *(const uint4*)(nb + c * TREE_BYTES + loc[c] * 16 + eoff);
      float xp[4], xl[4], xr[4];
      #pragma unroll
      for (int c = 0; c < 4; ++c) {
        int fp = r[c].w & 255, fl = (r[c].w >> 8) & 255, fr = (r[c].w >> 16) & 255;
        xp[c] = x_s[(fp << 6) + lane];
        xl[c] = x_s[(fl << 6) + lane];
        xr[c] = x_s[(fr << 6) + lane];
      }
      #pragma unroll
      for (int c = 0; c < 4; ++c) {
        bool c0  = (xp[c] >= __uint_as_float(r[c].x));
        float xc = c0 ? xr[c] : xl[c];
        float tc = __uint_as_float(c0 ? r[c].z : r[c].y);
        loc[c] = 4 * loc[c] + 2 * (int)c0 + (int)(xc >= tc);
      }
    }
    // ---- leaf values (L1-hot 1KB/tree) + direct scattered stores:
    //      offloads flush from the saturated LDS pipe to TCP/L2;
    //      16-tree lines merge in L2 across waves ----
    const int gb = b0 + lane;
    #pragma unroll
    for (int c = 0; c < 4; ++c) {
      int g  = gt0 + c;
      int cg = (g < NUM_TREES) ? g : 0;
      float v = vl[(size_t)cg * 256 + loc[c]];
      if (gb < BATCH && g < NUM_TREES)
        out[(size_t)gb * NUM_TREES + g] = v;
    }

    if (yt + 1 < YT) {
      __syncthreads();       // all x_s reads of this tile done
      xwrite();              // write-late (vmcnt wait lands here)
      __syncthreads();
    }
  }
}

// ================= fallback (no-ws path) =================
#define FB_BT 64
#define FB_TT 64
#define FB_TPR 16
#define FB_NROUNDS 4
#define FB_NTHREADS 1024
#define FB_XS (NFEAT * 64 * 4)
#define FB_NSU (FB_TPR * NUM_NODES)
#define FB_NS (FB_NSU * 8)
#define FB_OLD (FB_TT + 1)
#define FB_OS (FB_BT * FB_OLD * 4)
#define FB_SH (FB_XS + FB_NS + FB_OS)
#define FB_PREF ((FB_NSU + FB_NTHREADS - 1) / FB_NTHREADS)

__global__ __launch_bounds__(FB_NTHREADS, 1)
void fb_traverse(const float* __restrict__ x,
                 const float* __restrict__ thrg,
                 const int* __restrict__ featg,
                 const int* __restrict__ leftg,
                 const int* __restrict__ rightg,
                 const float* __restrict__ values,
                 float* __restrict__ out) {
  extern __shared__ unsigned char smem[];
  float* x_s     = (float*)smem;
  uint2* nodes_s = (uint2*)(smem + FB_XS);
  float* out_s   = (float*)(smem + FB_XS + FB_NS);
  const int tid = threadIdx.x, wid = tid >> 6, lane = tid & 63;
  const int b0 = blockIdx.y * FB_BT, t0 = blockIdx.x * FB_TT;
  uint2 pf[FB_PREF];
  auto load_round = [&](int rr) {
    const int gbase = (t0 + rr * FB_TPR) * NUM_NODES;
    #pragma unroll
    for (int k = 0; k < FB_PREF; ++k) {
      int fi = tid + k * FB_NTHREADS;
      uint2 v = make_uint2(0u, 0u);
      if (fi < FB_NSU) {
        int gi = gbase + fi;
        if (gi < FLAT_NODES) {
          uint32_t meta = (uint32_t)featg[gi] | ((uint32_t)leftg[gi] << 8) |
                          ((uint32_t)rightg[gi] << 20);
          v = make_uint2(__float_as_uint(thrg[gi]), meta);
        }
      }
      pf[k] = v;
    }
  };
  auto write_nodes = [&]() {
    #pragma unroll
    for (int k = 0; k < FB_PREF; ++k) {
      int fi = tid + k * FB_NTHREADS;
      if (fi < FB_NSU) nodes_s[fi] = pf[k];
    }
  };
  load_round(0);
  {
    const float4* xg = (const float4*)x;
    #pragma unroll
    for (int p = 0; p < (FB_BT * (NFEAT / 4)) / FB_NTHREADS; ++p) {
      int i = tid + p * FB_NTHREADS;
      int r = i >> 6, c = i & 63;
      int gb = b0 + r;
      float4 v = make_float4(0.f, 0.f, 0.f, 0.f);
      if (gb < BATCH) v = xg[gb * (NFEAT / 4) + c];
      int o = (c << 8) + (r ^ (c & 31));
      x_s[o] = v.x; x_s[o + 64] = v.y; x_s[o + 128] = v.z; x_s[o + 192] = v.w;
    }
  }
  write_nodes();
  __syncthreads();
  for (int r = 0; r < FB_NROUNDS; ++r) {
    if (r + 1 < FB_NROUNDS) load_round(r + 1);
    const uint2* nA = nodes_s + wid * NUM_NODES;
    const int tr0 = t0 + r * FB_TPR;
    const int gta = tr0 + wid;
    const int offA = (gta < NUM_TREES ? gta : 0) * NUM_NODES;
    uint2 na = nA[0];
    float va = 0.f;
    #pragma unroll
    for (int d = 0; d < DEPTH; ++d) {
      int fa = na.y & 0xFF;
      int la = (na.y >> 8) & 0xFFF;
      int ra = (int)(na.y >> 20);
      float xa = x_s[(fa << 6) + (lane ^ ((fa >> 2) & 31))];
      if (d < DEPTH - 1) {
        uint2 nla = nA[la], nra = nA[ra];
        na = (xa >= __uint_as_float(na.x)) ? nra : nla;
      } else {
        float vla = values[offA + la], vra = values[offA + ra];
        va = (xa >= __uint_as_float(na.x)) ? vra : vla;
      }
    }
    out_s[lane * FB_OLD + r * FB_TPR + wid] = va;
    __syncthreads();
    if (r + 1 < FB_NROUNDS) { write_nodes(); __syncthreads(); }
  }
  {
    const int gt = t0 + lane;
    #pragma unroll
    for (int p = 0; p < FB_BT / 16; ++p) {
      int rr = p * 16 + wid;
      int gb = b0 + rr;
      if (gb < BATCH && gt < NUM_TREES)
        out[gb * NUM_TREES + gt] = out_s[rr * FB_OLD + lane];
    }
  }
}

extern "C" void kernel_launch(void* const* d_in, const int* in_sizes, int n_in,
                              void* d_out, int out_size, void* d_ws, size_t ws_size,
                              hipStream_t stream) {
  const float* x          = (const float*)d_in[0];
  const float* thresholds = (const float*)d_in[1];
  const float* values     = (const float*)d_in[2];
  const int*   lefts      = (const int*)d_in[3];
  const int*   rights     = (const int*)d_in[4];
  const int*   features   = (const int*)d_in[5];
  float* out = (float*)d_out;

  if (ws_size >= WS_NEEDED) {
    unsigned char* ws = (unsigned char*)d_ws;
    unroll_kernel<<<NUM_TREES / 4, 256, 0, stream>>>(
        thresholds, features, lefts, rights, values, ws);
    hipFuncSetAttribute(reinterpret_cast<const void*>(traverse64),
                        hipFuncAttributeMaxDynamicSharedMemorySize, SH_BYTES);
    const int nbt = (BATCH + BT - 1) / BT;                  // 157
    dim3 grid((NUM_TREES + TT - 1) / TT, (nbt + YT - 1) / YT);  // 16 x 79
    traverse64<<<grid, NTHREADS, SH_BYTES, stream>>>(x, ws, out);
  } else {
    hipFuncSetAttribute(reinterpret_cast<const void*>(fb_traverse),
                        hipFuncAttributeMaxDynamicSharedMemorySize, FB_SH);
    dim3 grid((NUM_TREES + FB_TT - 1) / FB_TT, (BATCH + FB_BT - 1) / FB_BT);
    fb_traverse<<<grid, FB_NTHREADS, FB_SH, stream>>>(
        x, thresholds, features, lefts, rights, values, out);
  }
}

// Round 9
// 71.503 us; speedup vs baseline: 1.2381x; 1.2381x over previous
//
#include <hip/hip_runtime.h>
#include <stdint.h>

#define BATCH     10000
#define NUM_TREES 1000
#define NUM_NODES 511
#define NFEAT     256
#define DEPTH     8
#define FLAT_NODES (NUM_TREES * NUM_NODES)

// ---------------- 2-level fused record layout in d_ws ----------------
// Implicit depth-8 tree. Records exist at even depths {0,2,4,6}:
//   rec = {f32 thr_p, f32 thr_l, f32 thr_r, u32 f_p|f_l<<8|f_r<<16}
// rec index = EBASE[d/2] + local, EBASE = {0,1,5,21}; 85 recs = 1360 B/tree.
// One b128 read descends 2 levels: local' = 4*local + 2c0 + c1.
// Leaf (depth 8): vleaf[local] per tree (256 f32 = 1024 B).
#define TREE_BYTES 1360
#define VLEAF_OFF  ((size_t)NUM_TREES * TREE_BYTES)          // 1,360,000
#define WS_NEEDED  (VLEAF_OFF + (size_t)NUM_TREES * 256 * 4) // 2,384,000

// ---------------- traverse geometry ----------------
#define BT 64            // batch rows per block
#define TT 64            // trees per block
#define NTHREADS 1024    // 16 waves
#define XS_BYTES  (NFEAT * 64 * 4)               // 65536, [feat][64] swizzled
#define NS_BYTES  (TT * TREE_BYTES)              // 87040
#define SH_BYTES  (XS_BYTES + NS_BYTES)          // 152576 <= 160 KiB
#define NCHUNK    (NS_BYTES / 16)                // 5440 16B chunks
#define OUT_LD    68                             // floats; 17 float4/row

// async global->LDS copy, 16B per lane (dest = uniform base + lane*16)
__device__ __forceinline__ void glds16(const void* g, void* l) {
  __builtin_amdgcn_global_load_lds(
      (const __attribute__((address_space(1))) unsigned int*)g,
      (__attribute__((address_space(3))) unsigned int*)l, 16, 0, 0);
}

// ================= prepack: BFS-unroll into 2-level records =================
__global__ __launch_bounds__(256)
void unroll_kernel(const float* __restrict__ thr,
                   const int* __restrict__ feats,
                   const int* __restrict__ lefts,
                   const int* __restrict__ rights,
                   const float* __restrict__ values,
                   unsigned char* __restrict__ ws) {
  __shared__ uint16_t n_s[4][512];
  const int wv = threadIdx.x >> 6, lane = threadIdx.x & 63;
  const int tree = blockIdx.x * 4 + wv;          // grid=250 -> always < 1000
  const int base = tree * NUM_NODES;
  uint16_t* n = n_s[wv];
  uint4* rec   = (uint4*)(ws + (size_t)tree * TREE_BYTES);
  float* vleaf = (float*)(ws + VLEAF_OFF + (size_t)tree * 1024);

  if (lane == 0) n[0] = 0;
  __syncthreads();
  const int EBASE[4] = {0, 1, 5, 21};
  #pragma unroll
  for (int d = 0; d < 8; ++d) {
    const int lvl = (1 << d) - 1, cnt = 1 << d;
    for (int i = lane; i < cnt; i += 64) {
      int p  = lvl + i;
      int np = n[p];
      int nl = lefts[base + np], nr = rights[base + np];
      n[2 * p + 1] = (uint16_t)nl;
      n[2 * p + 2] = (uint16_t)nr;
      if ((d & 1) == 0) {
        uint32_t f3 = (uint32_t)feats[base + np] |
                      ((uint32_t)feats[base + nl] << 8) |
                      ((uint32_t)feats[base + nr] << 16);
        rec[EBASE[d >> 1] + i] =
            make_uint4(__float_as_uint(thr[base + np]),
                       __float_as_uint(thr[base + nl]),
                       __float_as_uint(thr[base + nr]), f3);
      }
    }
    __syncthreads();
  }
  #pragma unroll
  for (int i = lane; i < 256; i += 64)
    vleaf[i] = values[base + n[255 + i]];
}

// ================= main traversal =================
__global__ __launch_bounds__(NTHREADS, 1)
void traverse64(const float* __restrict__ x,
                const unsigned char* __restrict__ ws,
                float* __restrict__ out) {
  extern __shared__ unsigned char smem[];
  float* x_s = (float*)smem;                     // [256][64] swizzled
  unsigned char* nodes = smem + XS_BYTES;        // 64 trees * 1360 B
  float* out_s = (float*)nodes;                  // aliased after traversal

  const int tid  = threadIdx.x;
  const int wid  = tid >> 6;
  const int lane = tid & 63;
  const int b0   = blockIdx.y * BT;
  const int t0   = blockIdx.x * TT;

  // ---- node staging: async global->LDS b128, linear (no VGPR round-trip) ----
  {
    const unsigned char* src = ws + (size_t)t0 * TREE_BYTES;
    #pragma unroll
    for (int k = 0; k < 6; ++k) {
      int fi = tid + k * NTHREADS;
      if (fi < NCHUNK) glds16(src + (size_t)fi * 16, nodes + (size_t)fi * 16);
    }
  }
  // ---- x staging: coalesced float4 reads; swizzled conflict-free writes ----
  {
    const float4* xg = (const float4*)x;
    #pragma unroll
    for (int p = 0; p < 4; ++p) {
      int i = tid + p * NTHREADS;
      int r = i >> 6, c = i & 63;
      int gb = b0 + r;
      float4 v = (gb < BATCH) ? xg[(size_t)gb * 64 + c]
                              : make_float4(0.f, 0.f, 0.f, 0.f);
      int o = (c << 8) + (r ^ (c & 31));   // feat=4c+k at o + 64k; bank=(r^c)&31
      x_s[o]       = v.x;
      x_s[o + 64]  = v.y;
      x_s[o + 128] = v.z;
      x_s[o + 192] = v.w;
    }
  }
  __syncthreads();   // drains glds vmcnt + x_s writes

  // ---- traverse: wave owns 4 trees (ILP=4); lane = batch row ----
  // Non-speculative 2-level step: rec b128 -> gather x_parent -> pick child
  // (regs) -> gather x_child. 2 x-gathers per 2 levels (saves LDS-pipe time
  // vs 3-gather speculation; chain latency covered by 16 chains/SIMD).
  const unsigned char* nb = nodes + (size_t)(4 * wid) * TREE_BYTES;
  int loc[4] = {0, 0, 0, 0};
  #pragma unroll
  for (int it = 0; it < 4; ++it) {
    const int eoff = (it == 0) ? 0 : (it == 1) ? 16 : (it == 2) ? 80 : 336;
    uint4 r[4];
    #pragma unroll
    for (int c = 0; c < 4; ++c)
      r[c] = *(const uint4*)(nb + c * TREE_BYTES + loc[c] * 16 + eoff);
    float xp[4];
    #pragma unroll
    for (int c = 0; c < 4; ++c) {
      int fp = r[c].w & 255;
      xp[c] = x_s[(fp << 6) + (lane ^ ((fp >> 2) & 31))];
    }
    bool  c0[4]; int fc[4]; float tc[4];
    #pragma unroll
    for (int c = 0; c < 4; ++c) {
      c0[c] = (xp[c] >= __uint_as_float(r[c].x));
      fc[c] = c0[c] ? ((r[c].w >> 16) & 255) : ((r[c].w >> 8) & 255);
      tc[c] = __uint_as_float(c0[c] ? r[c].z : r[c].y);
    }
    float xc[4];
    #pragma unroll
    for (int c = 0; c < 4; ++c)
      xc[c] = x_s[(fc[c] << 6) + (lane ^ ((fc[c] >> 2) & 31))];
    #pragma unroll
    for (int c = 0; c < 4; ++c)
      loc[c] = 4 * loc[c] + 2 * (int)c0[c] + (int)(xc[c] >= tc[c]);
  }
  // ---- leaf values from prepacked table (L2-resident, 1 MB) ----
  const float* vl = (const float*)(ws + VLEAF_OFF);
  float4 v;
  {
    const int gt0 = t0 + 4 * wid;
    int g0 = (gt0 + 0 < NUM_TREES) ? gt0 + 0 : 0;
    int g1 = (gt0 + 1 < NUM_TREES) ? gt0 + 1 : 0;
    int g2 = (gt0 + 2 < NUM_TREES) ? gt0 + 2 : 0;
    int g3 = (gt0 + 3 < NUM_TREES) ? gt0 + 3 : 0;
    v = make_float4(vl[(size_t)g0 * 256 + loc[0]],
                    vl[(size_t)g1 * 256 + loc[1]],
                    vl[(size_t)g2 * 256 + loc[2]],
                    vl[(size_t)g3 * 256 + loc[3]]);
  }

  __syncthreads();                     // all node reads done -> alias as out_s
  *(float4*)(out_s + lane * OUT_LD + 4 * wid) = v;   // one b128 per lane
  __syncthreads();

  // ---- flush 64x64 tile, coalesced 64 B chunks ----
  #pragma unroll
  for (int k = 0; k < 4; ++k) {
    int rr = tid >> 4, col = (tid & 15) + 16 * k;
    int gb = b0 + rr, gt = t0 + col;
    if (gb < BATCH && gt < NUM_TREES)
      out[(size_t)gb * NUM_TREES + gt] = out_s[rr * OUT_LD + col];
  }
}

// ================= fallback (no-ws path) =================
#define FB_BT 64
#define FB_TT 64
#define FB_TPR 16
#define FB_NROUNDS 4
#define FB_NTHREADS 1024
#define FB_XS (NFEAT * 64 * 4)
#define FB_NSU (FB_TPR * NUM_NODES)
#define FB_NS (FB_NSU * 8)
#define FB_OLD (FB_TT + 1)
#define FB_OS (FB_BT * FB_OLD * 4)
#define FB_SH (FB_XS + FB_NS + FB_OS)
#define FB_PREF ((FB_NSU + FB_NTHREADS - 1) / FB_NTHREADS)

__global__ __launch_bounds__(FB_NTHREADS, 1)
void fb_traverse(const float* __restrict__ x,
                 const float* __restrict__ thrg,
                 const int* __restrict__ featg,
                 const int* __restrict__ leftg,
                 const int* __restrict__ rightg,
                 const float* __restrict__ values,
                 float* __restrict__ out) {
  extern __shared__ unsigned char smem[];
  float* x_s     = (float*)smem;
  uint2* nodes_s = (uint2*)(smem + FB_XS);
  float* out_s   = (float*)(smem + FB_XS + FB_NS);
  const int tid = threadIdx.x, wid = tid >> 6, lane = tid & 63;
  const int b0 = blockIdx.y * FB_BT, t0 = blockIdx.x * FB_TT;
  uint2 pf[FB_PREF];
  auto load_round = [&](int rr) {
    const int gbase = (t0 + rr * FB_TPR) * NUM_NODES;
    #pragma unroll
    for (int k = 0; k < FB_PREF; ++k) {
      int fi = tid + k * FB_NTHREADS;
      uint2 v = make_uint2(0u, 0u);
      if (fi < FB_NSU) {
        int gi = gbase + fi;
        if (gi < FLAT_NODES) {
          uint32_t meta = (uint32_t)featg[gi] | ((uint32_t)leftg[gi] << 8) |
                          ((uint32_t)rightg[gi] << 20);
          v = make_uint2(__float_as_uint(thrg[gi]), meta);
        }
      }
      pf[k] = v;
    }
  };
  auto write_nodes = [&]() {
    #pragma unroll
    for (int k = 0; k < FB_PREF; ++k) {
      int fi = tid + k * FB_NTHREADS;
      if (fi < FB_NSU) nodes_s[fi] = pf[k];
    }
  };
  load_round(0);
  {
    const float4* xg = (const float4*)x;
    #pragma unroll
    for (int p = 0; p < (FB_BT * (NFEAT / 4)) / FB_NTHREADS; ++p) {
      int i = tid + p * FB_NTHREADS;
      int r = i >> 6, c = i & 63;
      int gb = b0 + r;
      float4 v = make_float4(0.f, 0.f, 0.f, 0.f);
      if (gb < BATCH) v = xg[gb * (NFEAT / 4) + c];
      int o = (c << 8) + (r ^ (c & 31));
      x_s[o] = v.x; x_s[o + 64] = v.y; x_s[o + 128] = v.z; x_s[o + 192] = v.w;
    }
  }
  write_nodes();
  __syncthreads();
  for (int r = 0; r < FB_NROUNDS; ++r) {
    if (r + 1 < FB_NROUNDS) load_round(r + 1);
    const uint2* nA = nodes_s + wid * NUM_NODES;
    const int tr0 = t0 + r * FB_TPR;
    const int gta = tr0 + wid;
    const int offA = (gta < NUM_TREES ? gta : 0) * NUM_NODES;
    uint2 na = nA[0];
    float va = 0.f;
    #pragma unroll
    for (int d = 0; d < DEPTH; ++d) {
      int fa = na.y & 0xFF;
      int la = (na.y >> 8) & 0xFFF;
      int ra = (int)(na.y >> 20);
      float xa = x_s[(fa << 6) + (lane ^ ((fa >> 2) & 31))];
      if (d < DEPTH - 1) {
        uint2 nla = nA[la], nra = nA[ra];
        na = (xa >= __uint_as_float(na.x)) ? nra : nla;
      } else {
        float vla = values[offA + la], vra = values[offA + ra];
        va = (xa >= __uint_as_float(na.x)) ? vra : vla;
      }
    }
    out_s[lane * FB_OLD + r * FB_TPR + wid] = va;
    __syncthreads();
    if (r + 1 < FB_NROUNDS) { write_nodes(); __syncthreads(); }
  }
  {
    const int gt = t0 + lane;
    #pragma unroll
    for (int p = 0; p < FB_BT / 16; ++p) {
      int rr = p * 16 + wid;
      int gb = b0 + rr;
      if (gb < BATCH && gt < NUM_TREES)
        out[gb * NUM_TREES + gt] = out_s[rr * FB_OLD + lane];
    }
  }
}

extern "C" void kernel_launch(void* const* d_in, const int* in_sizes, int n_in,
                              void* d_out, int out_size, void* d_ws, size_t ws_size,
                              hipStream_t stream) {
  const float* x          = (const float*)d_in[0];
  const float* thresholds = (const float*)d_in[1];
  const float* values     = (const float*)d_in[2];
  const int*   lefts      = (const int*)d_in[3];
  const int*   rights     = (const int*)d_in[4];
  const int*   features   = (const int*)d_in[5];
  float* out = (float*)d_out;

  if (ws_size >= WS_NEEDED) {
    unsigned char* ws = (unsigned char*)d_ws;
    unroll_kernel<<<NUM_TREES / 4, 256, 0, stream>>>(
        thresholds, features, lefts, rights, values, ws);
    hipFuncSetAttribute(reinterpret_cast<const void*>(traverse64),
                        hipFuncAttributeMaxDynamicSharedMemorySize, SH_BYTES);
    dim3 grid((NUM_TREES + TT - 1) / TT, (BATCH + BT - 1) / BT);   // 16 x 157
    traverse64<<<grid, NTHREADS, SH_BYTES, stream>>>(x, ws, out);
  } else {
    hipFuncSetAttribute(reinterpret_cast<const void*>(fb_traverse),
                        hipFuncAttributeMaxDynamicSharedMemorySize, FB_SH);
    dim3 grid((NUM_TREES + FB_TT - 1) / FB_TT, (BATCH + FB_BT - 1) / FB_BT);
    fb_traverse<<<grid, FB_NTHREADS, FB_SH, stream>>>(
        x, thresholds, features, lefts, rights, values, out);
  }
}

// Round 10
// 55.643 us; speedup vs baseline: 1.5910x; 1.2850x over previous
//
#include <hip/hip_runtime.h>
#include <stdint.h>

#define BATCH     10000
#define NUM_TREES 1000
#define NUM_NODES 511
#define NFEAT     256
#define DEPTH     8
#define FLAT_NODES (NUM_TREES * NUM_NODES)

// ---------------- 2-level fused record layout in d_ws ----------------
// Implicit depth-8 tree. Records exist at even depths {0,2,4,6}:
//   rec = {f32 thr_p, f32 thr_l, f32 thr_r, u32 f_p|f_l<<8|f_r<<16}
// rec index = EBASE[d/2] + local, EBASE = {0,1,5,21}; 85 recs = 1360 B/tree.
// One b128 read descends 2 levels: local' = 4*local + 2c0 + c1.
// Leaf (depth 8): vleaf[local] per tree (256 f32 = 1024 B).
#define TREE_BYTES 1360
#define VLEAF_OFF  ((size_t)NUM_TREES * TREE_BYTES)          // 1,360,000
#define WS_NEEDED  (VLEAF_OFF + (size_t)NUM_TREES * 256 * 4) // 2,384,000

// ---------------- traverse geometry (2 blocks/CU, 32 waves/CU) ----------------
#define BT 64            // batch rows per block
#define TT 64            // trees per block
#define NTHREADS 1024    // 16 waves
#define XS_BYTES  (NFEAT * 64 * 4)               // 65536, [feat][64] swizzled
#define OUT_LD    36                             // f4-aligned, half-tile bounce
#define OS_BYTES  (64 * OUT_LD * 4)              // 9216
#define SH_BYTES  (XS_BYTES + OS_BYTES)          // 74752 <= 81920 -> 2 blocks/CU

// ================= prepack: BFS-unroll into 2-level records =================
__global__ __launch_bounds__(256)
void unroll_kernel(const float* __restrict__ thr,
                   const int* __restrict__ feats,
                   const int* __restrict__ lefts,
                   const int* __restrict__ rights,
                   const float* __restrict__ values,
                   unsigned char* __restrict__ ws) {
  __shared__ uint16_t n_s[4][512];
  const int wv = threadIdx.x >> 6, lane = threadIdx.x & 63;
  const int tree = blockIdx.x * 4 + wv;          // grid=250 -> always < 1000
  const int base = tree * NUM_NODES;
  uint16_t* n = n_s[wv];
  uint4* rec   = (uint4*)(ws + (size_t)tree * TREE_BYTES);
  float* vleaf = (float*)(ws + VLEAF_OFF + (size_t)tree * 1024);

  if (lane == 0) n[0] = 0;
  __syncthreads();
  const int EBASE[4] = {0, 1, 5, 21};
  #pragma unroll
  for (int d = 0; d < 8; ++d) {
    const int lvl = (1 << d) - 1, cnt = 1 << d;
    for (int i = lane; i < cnt; i += 64) {
      int p  = lvl + i;
      int np = n[p];
      int nl = lefts[base + np], nr = rights[base + np];
      n[2 * p + 1] = (uint16_t)nl;
      n[2 * p + 2] = (uint16_t)nr;
      if ((d & 1) == 0) {
        uint32_t f3 = (uint32_t)feats[base + np] |
                      ((uint32_t)feats[base + nl] << 8) |
                      ((uint32_t)feats[base + nr] << 16);
        rec[EBASE[d >> 1] + i] =
            make_uint4(__float_as_uint(thr[base + np]),
                       __float_as_uint(thr[base + nl]),
                       __float_as_uint(thr[base + nr]), f3);
      }
    }
    __syncthreads();
  }
  #pragma unroll
  for (int i = lane; i < 256; i += 64)
    vleaf[i] = values[base + n[255 + i]];
}

// ================= main traversal =================
// Nodes are NOT LDS-staged: per-wave record reads are 64x16B within one
// 1360 B tree region (<=8 cache lines/instr, L1/L2-hot) -> TCP path runs
// in parallel with the LDS x-gathers, and the freed LDS gives 2 blocks/CU.
__global__ __launch_bounds__(NTHREADS, 8)   // 8 waves/EU = 2 blocks/CU
void traverse64(const float* __restrict__ x,
                const unsigned char* __restrict__ ws,
                float* __restrict__ out) {
  extern __shared__ unsigned char smem[];
  float* x_s   = (float*)smem;                   // [256][64] swizzled
  float* out_s = (float*)(smem + XS_BYTES);      // [64][OUT_LD] half-tile

  const int tid  = threadIdx.x;
  const int wid  = tid >> 6;
  const int lane = tid & 63;
  const int b0   = blockIdx.y * BT;
  const int t0   = blockIdx.x * TT;

  // ---- x staging: coalesced float4 reads; swizzled conflict-free writes ----
  {
    const float4* xg = (const float4*)x;
    #pragma unroll
    for (int p = 0; p < 4; ++p) {
      int i = tid + p * NTHREADS;
      int r = i >> 6, c = i & 63;
      int gb = b0 + r;
      float4 v = (gb < BATCH) ? xg[(size_t)gb * 64 + c]
                              : make_float4(0.f, 0.f, 0.f, 0.f);
      int o = (c << 8) + (r ^ (c & 31));   // feat=4c+k at o + 64k; bank=(r^c)&31
      x_s[o]       = v.x;
      x_s[o + 64]  = v.y;
      x_s[o + 128] = v.z;
      x_s[o + 192] = v.w;
    }
  }
  __syncthreads();

  // ---- traverse: wave owns 4 trees (ILP=4); lane = batch row ----
  // rec b128 from GLOBAL (L1/L2-hot) -> gather x_parent (LDS) -> pick child
  // in regs -> gather x_child (LDS).
  const unsigned char* nb = ws + (size_t)(t0 + 4 * wid) * TREE_BYTES;
  int loc[4] = {0, 0, 0, 0};
  #pragma unroll
  for (int it = 0; it < 4; ++it) {
    const int eoff = (it == 0) ? 0 : (it == 1) ? 16 : (it == 2) ? 80 : 336;
    uint4 r[4];
    #pragma unroll
    for (int c = 0; c < 4; ++c)
      r[c] = *(const uint4*)(nb + (size_t)c * TREE_BYTES + loc[c] * 16 + eoff);
    float xp[4];
    #pragma unroll
    for (int c = 0; c < 4; ++c) {
      int fp = r[c].w & 255;
      xp[c] = x_s[(fp << 6) + (lane ^ ((fp >> 2) & 31))];
    }
    bool  c0[4]; int fc[4]; float tc[4];
    #pragma unroll
    for (int c = 0; c < 4; ++c) {
      c0[c] = (xp[c] >= __uint_as_float(r[c].x));
      fc[c] = c0[c] ? ((r[c].w >> 16) & 255) : ((r[c].w >> 8) & 255);
      tc[c] = __uint_as_float(c0[c] ? r[c].z : r[c].y);
    }
    float xc[4];
    #pragma unroll
    for (int c = 0; c < 4; ++c)
      xc[c] = x_s[(fc[c] << 6) + (lane ^ ((fc[c] >> 2) & 31))];
    #pragma unroll
    for (int c = 0; c < 4; ++c)
      loc[c] = 4 * loc[c] + 2 * (int)c0[c] + (int)(xc[c] >= tc[c]);
  }
  // ---- leaf values from prepacked table (L2-resident, 1 MB) ----
  const float* vl = (const float*)(ws + VLEAF_OFF);
  float4 v;
  {
    const int gt0 = t0 + 4 * wid;
    int g0 = (gt0 + 0 < NUM_TREES) ? gt0 + 0 : 0;
    int g1 = (gt0 + 1 < NUM_TREES) ? gt0 + 1 : 0;
    int g2 = (gt0 + 2 < NUM_TREES) ? gt0 + 2 : 0;
    int g3 = (gt0 + 3 < NUM_TREES) ? gt0 + 3 : 0;
    v = make_float4(vl[(size_t)g0 * 256 + loc[0]],
                    vl[(size_t)g1 * 256 + loc[1]],
                    vl[(size_t)g2 * 256 + loc[2]],
                    vl[(size_t)g3 * 256 + loc[3]]);
  }

  // ---- out bounce, two tree-half passes through [64][36] ----
  // pass 0: waves 0..7 (tree cols 0..31)
  if (wid < 8)
    *(float4*)(out_s + lane * OUT_LD + 4 * wid) = v;
  __syncthreads();
  {
    int col = tid & 31, rr = tid >> 5;
    #pragma unroll
    for (int k = 0; k < 2; ++k) {
      int row = rr + 32 * k;
      int gb = b0 + row, gt = t0 + col;
      if (gb < BATCH && gt < NUM_TREES)
        out[(size_t)gb * NUM_TREES + gt] = out_s[row * OUT_LD + col];
    }
  }
  __syncthreads();
  // pass 1: waves 8..15 (tree cols 32..63)
  if (wid >= 8)
    *(float4*)(out_s + lane * OUT_LD + 4 * (wid - 8)) = v;
  __syncthreads();
  {
    int col = tid & 31, rr = tid >> 5;
    #pragma unroll
    for (int k = 0; k < 2; ++k) {
      int row = rr + 32 * k;
      int gb = b0 + row, gt = t0 + 32 + col;
      if (gb < BATCH && gt < NUM_TREES)
        out[(size_t)gb * NUM_TREES + gt] = out_s[row * OUT_LD + col];
    }
  }
}

// ================= fallback (no-ws path) =================
#define FB_BT 64
#define FB_TT 64
#define FB_TPR 16
#define FB_NROUNDS 4
#define FB_NTHREADS 1024
#define FB_XS (NFEAT * 64 * 4)
#define FB_NSU (FB_TPR * NUM_NODES)
#define FB_NS (FB_NSU * 8)
#define FB_OLD (FB_TT + 1)
#define FB_OS (FB_BT * FB_OLD * 4)
#define FB_SH (FB_XS + FB_NS + FB_OS)
#define FB_PREF ((FB_NSU + FB_NTHREADS - 1) / FB_NTHREADS)

__global__ __launch_bounds__(FB_NTHREADS, 1)
void fb_traverse(const float* __restrict__ x,
                 const float* __restrict__ thrg,
                 const int* __restrict__ featg,
                 const int* __restrict__ leftg,
                 const int* __restrict__ rightg,
                 const float* __restrict__ values,
                 float* __restrict__ out) {
  extern __shared__ unsigned char smem[];
  float* x_s     = (float*)smem;
  uint2* nodes_s = (uint2*)(smem + FB_XS);
  float* out_s   = (float*)(smem + FB_XS + FB_NS);
  const int tid = threadIdx.x, wid = tid >> 6, lane = tid & 63;
  const int b0 = blockIdx.y * FB_BT, t0 = blockIdx.x * FB_TT;
  uint2 pf[FB_PREF];
  auto load_round = [&](int rr) {
    const int gbase = (t0 + rr * FB_TPR) * NUM_NODES;
    #pragma unroll
    for (int k = 0; k < FB_PREF; ++k) {
      int fi = tid + k * FB_NTHREADS;
      uint2 v = make_uint2(0u, 0u);
      if (fi < FB_NSU) {
        int gi = gbase + fi;
        if (gi < FLAT_NODES) {
          uint32_t meta = (uint32_t)featg[gi] | ((uint32_t)leftg[gi] << 8) |
                          ((uint32_t)rightg[gi] << 20);
          v = make_uint2(__float_as_uint(thrg[gi]), meta);
        }
      }
      pf[k] = v;
    }
  };
  auto write_nodes = [&]() {
    #pragma unroll
    for (int k = 0; k < FB_PREF; ++k) {
      int fi = tid + k * FB_NTHREADS;
      if (fi < FB_NSU) nodes_s[fi] = pf[k];
    }
  };
  load_round(0);
  {
    const float4* xg = (const float4*)x;
    #pragma unroll
    for (int p = 0; p < (FB_BT * (NFEAT / 4)) / FB_NTHREADS; ++p) {
      int i = tid + p * FB_NTHREADS;
      int r = i >> 6, c = i & 63;
      int gb = b0 + r;
      float4 v = make_float4(0.f, 0.f, 0.f, 0.f);
      if (gb < BATCH) v = xg[gb * (NFEAT / 4) + c];
      int o = (c << 8) + (r ^ (c & 31));
      x_s[o] = v.x; x_s[o + 64] = v.y; x_s[o + 128] = v.z; x_s[o + 192] = v.w;
    }
  }
  write_nodes();
  __syncthreads();
  for (int r = 0; r < FB_NROUNDS; ++r) {
    if (r + 1 < FB_NROUNDS) load_round(r + 1);
    const uint2* nA = nodes_s + wid * NUM_NODES;
    const int tr0 = t0 + r * FB_TPR;
    const int gta = tr0 + wid;
    const int offA = (gta < NUM_TREES ? gta : 0) * NUM_NODES;
    uint2 na = nA[0];
    float va = 0.f;
    #pragma unroll
    for (int d = 0; d < DEPTH; ++d) {
      int fa = na.y & 0xFF;
      int la = (na.y >> 8) & 0xFFF;
      int ra = (int)(na.y >> 20);
      float xa = x_s[(fa << 6) + (lane ^ ((fa >> 2) & 31))];
      if (d < DEPTH - 1) {
        uint2 nla = nA[la], nra = nA[ra];
        na = (xa >= __uint_as_float(na.x)) ? nra : nla;
      } else {
        float vla = values[offA + la], vra = values[offA + ra];
        va = (xa >= __uint_as_float(na.x)) ? vra : vla;
      }
    }
    out_s[lane * FB_OLD + r * FB_TPR + wid] = va;
    __syncthreads();
    if (r + 1 < FB_NROUNDS) { write_nodes(); __syncthreads(); }
  }
  {
    const int gt = t0 + lane;
    #pragma unroll
    for (int p = 0; p < FB_BT / 16; ++p) {
      int rr = p * 16 + wid;
      int gb = b0 + rr;
      if (gb < BATCH && gt < NUM_TREES)
        out[gb * NUM_TREES + gt] = out_s[rr * FB_OLD + lane];
    }
  }
}

extern "C" void kernel_launch(void* const* d_in, const int* in_sizes, int n_in,
                              void* d_out, int out_size, void* d_ws, size_t ws_size,
                              hipStream_t stream) {
  const float* x          = (const float*)d_in[0];
  const float* thresholds = (const float*)d_in[1];
  const float* values     = (const float*)d_in[2];
  const int*   lefts      = (const int*)d_in[3];
  const int*   rights     = (const int*)d_in[4];
  const int*   features   = (const int*)d_in[5];
  float* out = (float*)d_out;

  if (ws_size >= WS_NEEDED) {
    unsigned char* ws = (unsigned char*)d_ws;
    unroll_kernel<<<NUM_TREES / 4, 256, 0, stream>>>(
        thresholds, features, lefts, rights, values, ws);
    hipFuncSetAttribute(reinterpret_cast<const void*>(traverse64),
                        hipFuncAttributeMaxDynamicSharedMemorySize, SH_BYTES);
    dim3 grid((NUM_TREES + TT - 1) / TT, (BATCH + BT - 1) / BT);   // 16 x 157
    traverse64<<<grid, NTHREADS, SH_BYTES, stream>>>(x, ws, out);
  } else {
    hipFuncSetAttribute(reinterpret_cast<const void*>(fb_traverse),
                        hipFuncAttributeMaxDynamicSharedMemorySize, FB_SH);
    dim3 grid((NUM_TREES + FB_TT - 1) / FB_TT, (BATCH + FB_BT - 1) / FB_BT);
    fb_traverse<<<grid, FB_NTHREADS, FB_SH, stream>>>(
        x, thresholds, features, lefts, rights, values, out);
  }
}